// Round 11
// baseline (132.802 us; speedup 1.0000x reference)
//
#include <hip/hip_runtime.h>
#include <hip/hip_bf16.h>

#define B_ 2
#define L_ 2048
#define C_ 1024
#define H_ 16
#define DK_ 64
#define M_ (B_*L_)            // 4096 rows
#define MASK_VALF (-32767.0f)
#define LOG2E 1.44269504088896f

typedef __attribute__((ext_vector_type(8))) short bf16x8;
typedef __attribute__((ext_vector_type(4))) float f32x4;
typedef __attribute__((ext_vector_type(4))) unsigned uint4v;

static __device__ __forceinline__ short f2bf(float f) {
    __hip_bfloat16 h = __float2bfloat16(f);
    return *reinterpret_cast<short*>(&h);
}

// raw v_exp_f32: 1 TRANS inst, flushes exp2(-32767) -> 0 (no libm range fixup)
static __device__ __forceinline__ float exp2_raw(float x) {
    float r;
    asm("v_exp_f32 %0, %1" : "=v"(r) : "v"(x));
    return r;
}
// pack 2 f32 -> 2 bf16 (RNE) in one inst
static __device__ __forceinline__ unsigned cvt_pk_bf16(float lo, float hi) {
    unsigned r;
    asm("v_cvt_pk_bf16_f32 %0, %1, %2" : "=v"(r) : "v"(lo), "v"(hi));
    return r;
}

// ---------------- Fused prep: LN | wconv | maskpack (grid-partitioned) ----------------
__global__ __launch_bounds__(256) void prep_kernel(
    const float* __restrict__ qx, const float* __restrict__ kx, const float* __restrict__ vx,
    const float* __restrict__ g, const float* __restrict__ bias,
    short* __restrict__ qn, short* __restrict__ kn, short* __restrict__ vn,
    const float* __restrict__ wq, const float* __restrict__ wk,
    const float* __restrict__ wv, const float* __restrict__ wo,
    short* __restrict__ wqt, short* __restrict__ wkt,
    short* __restrict__ wvt, short* __restrict__ wot,
    const int* __restrict__ mask, unsigned long long* __restrict__ bits)
{
    const int bid = blockIdx.x;
    const int t = threadIdx.x;

    if (bid < 3*M_) {                          // ---- LayerNorm ----
        const int row = bid & (M_ - 1);
        const int which = bid >> 12;
        const float* src = (which == 0) ? qx : (which == 1) ? kx : vx;
        short* dst = (which == 0) ? qn : (which == 1) ? kn : vn;
        src += (size_t)row * C_;
        dst += (size_t)row * C_;
        float4 xv = reinterpret_cast<const float4*>(src)[t];
        float s  = xv.x + xv.y + xv.z + xv.w;
        float s2 = xv.x*xv.x + xv.y*xv.y + xv.z*xv.z + xv.w*xv.w;
        #pragma unroll
        for (int off = 32; off > 0; off >>= 1) {
            s  += __shfl_down(s, off);
            s2 += __shfl_down(s2, off);
        }
        __shared__ float red[8];
        const int wid = t >> 6, lane = t & 63;
        if (lane == 0) { red[wid] = s; red[4 + wid] = s2; }
        __syncthreads();
        const float ts  = red[0] + red[1] + red[2] + red[3];
        const float ts2 = red[4] + red[5] + red[6] + red[7];
        const float mu  = ts * (1.0f / C_);
        const float var = ts2 * (1.0f / C_) - mu * mu;
        const float rs  = rsqrtf(var + 1e-5f);
        float4 gv = reinterpret_cast<const float4*>(g)[t];
        float4 bv = reinterpret_cast<const float4*>(bias)[t];
        short4 o;
        o.x = f2bf((xv.x - mu) * rs * gv.x + bv.x);
        o.y = f2bf((xv.y - mu) * rs * gv.y + bv.y);
        o.z = f2bf((xv.z - mu) * rs * gv.z + bv.z);
        o.w = f2bf((xv.w - mu) * rs * gv.w + bv.w);
        reinterpret_cast<short4*>(dst)[t] = o;
    } else if (bid < 3*M_ + 4096) {            // ---- weight transpose+convert ----
        const int b2 = bid - 3*M_;
        const int mz = b2 >> 10;
        const int bx = b2 & 31, by = (b2 >> 5) & 31;
        const float* w = (mz==0)?wq:(mz==1)?wk:(mz==2)?wv:wo;
        short* wt = (mz==0)?wqt:(mz==1)?wkt:(mz==2)?wvt:wot;
        __shared__ float tile[32][33];
        const int tx = t & 31, ty = t >> 5;    // 32 x 8
        const int k0 = bx * 32, n0 = by * 32;
        #pragma unroll
        for (int r = 0; r < 4; r++) {
            const int k = k0 + ty + r*8;
            tile[ty + r*8][tx] = w[(size_t)k * 1024 + n0 + tx];
        }
        __syncthreads();
        #pragma unroll
        for (int r = 0; r < 4; r++) {
            const int n = n0 + ty + r*8;
            wt[(size_t)n * 1024 + k0 + tx] = f2bf(tile[tx][ty + r*8]);
        }
    } else {                                    // ---- mask pack ----
        const int b3 = bid - (3*M_ + 4096);
        const int gw = b3 * 4 + (t >> 6);       // word index 0..131071
        const int lane = t & 63;
        const int k = (gw & 31) * 64 + lane;
        const int rowq = gw >> 5;               // b*L + q
        const int v = mask[(size_t)rowq * L_ + k];
        unsigned long long bal = __ballot(v != 0);
        if (lane == 0) bits[gw] = bal;
    }
}

// ---------------- GEMM core (double-buffered): C128x128 = A * Bt^T, BK=32 ----------------
// lds must be 16384 shorts (32 KB): 2 buffers x (A 128x32 | B 128x32).
__device__ __forceinline__ void gemm_core_128(
    const short* __restrict__ Abf, const short* __restrict__ Bt,
    int m0, int n0, short* lds, f32x4 (&acc)[4][4])
{
    const int t = threadIdx.x, w = t >> 6, l = t & 63;
    const int wm = w >> 1, wn = w & 1;
    const int l15 = l & 15, l4 = l >> 4;
    const int srow = t >> 2, scol = (t & 3) * 8;
    const short* aS = Abf + (size_t)(m0 + srow) * 1024 + scol;
    const short* bS = Bt  + (size_t)(n0 + srow) * 1024 + scol;
    char* lb = (char*)lds;
    const int wb = w * 1024;

    #define GSTAGE(buf, kt) do {                                                   \
        const int ko = (kt) * 32;                                                  \
        char* dst = lb + (buf)*16384;                                              \
        __builtin_amdgcn_global_load_lds(                                          \
            (const __attribute__((address_space(1))) void*)(aS + ko),              \
            (__attribute__((address_space(3))) void*)(dst + wb), 16, 0, 0);        \
        __builtin_amdgcn_global_load_lds(                                          \
            (const __attribute__((address_space(1))) void*)(aS + 64*1024 + ko),    \
            (__attribute__((address_space(3))) void*)(dst + wb + 4096), 16, 0, 0); \
        __builtin_amdgcn_global_load_lds(                                          \
            (const __attribute__((address_space(1))) void*)(bS + ko),              \
            (__attribute__((address_space(3))) void*)(dst + 8192 + wb), 16, 0, 0); \
        __builtin_amdgcn_global_load_lds(                                          \
            (const __attribute__((address_space(1))) void*)(bS + 64*1024 + ko),    \
            (__attribute__((address_space(3))) void*)(dst + 8192 + wb + 4096), 16, 0, 0); \
    } while (0)

    GSTAGE(0, 0);
    for (int kt = 0; kt < 32; ++kt) {
        __syncthreads();                            // drains tile kt's loads
        if (kt + 1 < 32) GSTAGE((kt + 1) & 1, kt + 1);   // prefetch overlaps compute
        const short* Lb = lds + (kt & 1) * 8192;
        bf16x8 af[4], bfr[4];
        #pragma unroll
        for (int fm = 0; fm < 4; fm++)
            af[fm] = *reinterpret_cast<const bf16x8*>(&Lb[(wm*64 + fm*16 + l15)*32 + l4*8]);
        #pragma unroll
        for (int fn = 0; fn < 4; fn++)
            bfr[fn] = *reinterpret_cast<const bf16x8*>(&Lb[4096 + (wn*64 + fn*16 + l15)*32 + l4*8]);
        #pragma unroll
        for (int fm = 0; fm < 4; fm++)
            #pragma unroll
            for (int fn = 0; fn < 4; fn++)
                acc[fm][fn] = __builtin_amdgcn_mfma_f32_16x16x32_bf16(af[fm], bfr[fn], acc[fm][fn], 0, 0, 0);
    }
    #undef GSTAGE
}

// ---------------- Projections: q/k/v = LN(x) @ W + b, split heads ----------------
// q pre-scaled by (1/8)*log2e (exp2-domain softmax).
// V written TRANSPOSED per head with k-slot permutation within each 64-block:
// slot(k) = (k&~63) | (qd*32 + g*8 + h*4 + r) for k%64 = qd*32 + h*16 + g*4 + r.
// XCD-aware block swizzle: 256 blocks/slice, 256%8==0 -> bijective.
__global__ __launch_bounds__(256) void gemm_proj(
    const short* __restrict__ qn, const short* __restrict__ kn, const short* __restrict__ vn,
    const short* __restrict__ wqt, const short* __restrict__ wkt, const short* __restrict__ wvt,
    const float* __restrict__ bq, const float* __restrict__ bk, const float* __restrict__ bv,
    short* __restrict__ qb, short* __restrict__ kb, short* __restrict__ vtb)
{
    const int pi = blockIdx.y;
    const short* Abf = (pi==0)?qn:(pi==1)?kn:vn;
    const short* Bt  = (pi==0)?wqt:(pi==1)?wkt:wvt;
    const float* bias= (pi==0)?bq:(pi==1)?bk:bv;
    short* outp      = (pi==0)?qb:(pi==1)?kb:vtb;
    const float scale = (pi==0)?(0.125f*LOG2E):1.0f;

    __shared__ short lds[16384];
    const int bx0 = blockIdx.x;
    const int bx = (bx0 & 7) * 32 + (bx0 >> 3);     // XCD swizzle (bijective, 256%8==0)
    const int m0 = (bx >> 3) * 128, n0 = (bx & 7) * 128;
    f32x4 acc[4][4] = {};
    gemm_core_128(Abf, Bt, m0, n0, lds, acc);

    const int t = threadIdx.x, w = t >> 6, l = t & 63;
    const int wm = w >> 1, wn = w & 1, l15 = l & 15, l4 = l >> 4;
    #pragma unroll
    for (int fn = 0; fn < 4; fn++) {
        const int col = n0 + wn*64 + fn*16 + l15;
        const float bsv = bias[col];
        const int h = col >> 6, dk = col & 63;
        #pragma unroll
        for (int fm = 0; fm < 4; fm++) {
            const int row0 = m0 + wm*64 + fm*16 + l4*4;
            const int bb = row0 >> 11, lr0 = row0 & (L_ - 1);
            if (pi == 2) {
                // x = lr0 & 63 = fm*16 + l4*4; perm: qd=fm>>1, h=fm&1, g=l4
                const int lrp = (lr0 & ~63) | ((fm >> 1)*32 + l4*8 + (fm & 1)*4);
                short4 s4;
                #pragma unroll
                for (int r = 0; r < 4; r++)
                    ((short*)&s4)[r] = f2bf(acc[fm][fn][r] + bsv);
                *reinterpret_cast<short4*>(
                    &outp[(((size_t)bb*H_ + h)*DK_ + dk)*L_ + lrp]) = s4;
            } else {
                #pragma unroll
                for (int r = 0; r < 4; r++) {
                    const float vvf = (acc[fm][fn][r] + bsv) * scale;
                    outp[(((size_t)bb*H_ + h)*L_ + lr0 + r)*DK_ + dk] = f2bf(vvf);
                }
            }
        }
    }
}

// ---------------- Output projection: out = z @ wo + bo (fp32 out), 64x128 tiles ----------
// 512 blocks (2/CU), 4 waves. Wave (wm,wn) owns 32x64; acc[2][4]. XCD swizzle.
__global__ __launch_bounds__(256) void gemm_out_k(
    const short* __restrict__ zb, const short* __restrict__ wot,
    const float* __restrict__ bo, float* __restrict__ out)
{
    __shared__ short lds[12288];   // 2 x (A 64x32 = 2048 sh | B 128x32 = 4096 sh)
    const int t = threadIdx.x, w = t >> 6, l = t & 63;
    const int wm = w >> 1, wn = w & 1;
    const int l15 = l & 15, l4 = l >> 4;
    const int bx0 = blockIdx.x;
    const int bx = (bx0 & 7) * 64 + (bx0 >> 3);     // XCD swizzle (512%8==0)
    const int m0 = (bx >> 3) * 64, n0 = (bx & 7) * 128;

    const int srow = l >> 2, scol = (l & 3) * 8;     // 16 rows x 64B per 1KB chunk
    const short* aS = zb  + (size_t)(m0 + w*16 + srow) * 1024 + scol;
    const short* bS = wot + (size_t)(n0 + w*32 + srow) * 1024 + scol;
    char* lb = (char*)lds;

    f32x4 acc[2][4] = {};

    #define OSTAGE(buf, kt) do {                                                    \
        const int ko = (kt) * 32;                                                   \
        char* dst = lb + (buf)*12288;                                               \
        __builtin_amdgcn_global_load_lds(                                           \
            (const __attribute__((address_space(1))) void*)(aS + ko),               \
            (__attribute__((address_space(3))) void*)(dst + w*1024), 16, 0, 0);     \
        __builtin_amdgcn_global_load_lds(                                           \
            (const __attribute__((address_space(1))) void*)(bS + ko),               \
            (__attribute__((address_space(3))) void*)(dst + 4096 + w*2048), 16, 0, 0); \
        __builtin_amdgcn_global_load_lds(                                           \
            (const __attribute__((address_space(1))) void*)(bS + 16*1024 + ko),     \
            (__attribute__((address_space(3))) void*)(dst + 4096 + w*2048 + 1024), 16, 0, 0); \
    } while (0)

    OSTAGE(0, 0);
    for (int kt = 0; kt < 32; ++kt) {
        __syncthreads();
        if (kt + 1 < 32) OSTAGE((kt + 1) & 1, kt + 1);
        const short* Lb = lds + (kt & 1) * 6144;
        bf16x8 af[2], bfr[4];
        #pragma unroll
        for (int fm = 0; fm < 2; fm++)
            af[fm] = *reinterpret_cast<const bf16x8*>(&Lb[(wm*32 + fm*16 + l15)*32 + l4*8]);
        #pragma unroll
        for (int fn = 0; fn < 4; fn++)
            bfr[fn] = *reinterpret_cast<const bf16x8*>(&Lb[2048 + (wn*64 + fn*16 + l15)*32 + l4*8]);
        #pragma unroll
        for (int fm = 0; fm < 2; fm++)
            #pragma unroll
            for (int fn = 0; fn < 4; fn++)
                acc[fm][fn] = __builtin_amdgcn_mfma_f32_16x16x32_bf16(af[fm], bfr[fn], acc[fm][fn], 0, 0, 0);
    }
    #undef OSTAGE

    #pragma unroll
    for (int fn = 0; fn < 4; fn++) {
        const int col = n0 + wn*64 + fn*16 + l15;
        const float bsv = bo[col];
        #pragma unroll
        for (int fm = 0; fm < 2; fm++) {
            #pragma unroll
            for (int r = 0; r < 4; r++) {
                const int row = m0 + wm*32 + fm*16 + l4*4 + r;
                out[(size_t)row * C_ + col] = acc[fm][fn][r] + bsv;
            }
        }
    }
}

// ---------------- Flash attention v11: v10 with correct 32KB LDS (occupancy fix) --------
// v10 accidentally declared SM[65536] while addressing only 32KB -> 2 blocks/CU.
// 32KB gives 4 blocks/CU = 32 waves/CU (hardware max) for this latency-bound kernel.
__global__ __launch_bounds__(512) void attn_kernel(
    const short* __restrict__ qbuf, const short* __restrict__ kbuf, const short* __restrict__ vt,
    const unsigned long long* __restrict__ mbits, short* __restrict__ zb)
{
    __shared__ char SM[32768];    // [buf:2][K 8KB | V 8KB]
    const int t = threadIdx.x, w = t >> 6, l = t & 63;
    const int l15 = l & 15, l4 = l >> 4;
    const int bid = blockIdx.x;
    const int bh = bid & 31, qb = bid >> 5;
    const int qt0 = qb * 128;
    const int b = bh >> 4, h = bh & 15;
    const size_t base  = (size_t)bh * L_ * DK_;   // q,k: [l][d]
    const size_t vbase = (size_t)bh * DK_ * L_;   // vt:  [d][k-permuted]

    const int q = qt0 + w*16 + l15;               // this lane's softmax row

    // staging geometry (wave w stages LDS rows w*8..w*8+7; swizzled source)
    const int srow = w*8 + (l >> 3);
    const int scolb = ((l & 7) * 16) ^ ((srow & 7) << 4);

    // persistent global staging pointers: even/odd tile; advance by 2-tile stride
    const char* gkA = (const char*)(kbuf + base + (size_t)srow*DK_) + scolb;
    const char* gkB = gkA + 8192;                 // K tile stride = 64*64*2 B
    const char* gvA = (const char*)(vt + vbase + (size_t)srow*L_) + scolb;
    const char* gvB = gvA + 128;                  // V tile stride = 64 cols * 2 B

    // LDS staging destinations (linear, wave-contiguous)
    char* kd0 = SM + w*1024;
    char* vd0 = SM + 8192 + w*1024;
    char* kd1 = SM + 16384 + w*1024;
    char* vd1 = SM + 16384 + 8192 + w*1024;

    // per-lane LDS read bases; all reads = base + compile-time immediate
    const int sw = (l15 & 7) << 4;
    const char* pa = SM + l15*128 + ((l4*16) ^ sw);
    const char* pb = SM + l15*128 + ((64 + l4*16) ^ sw);

    bf16x8 qf[2];
    #pragma unroll
    for (int kk = 0; kk < 2; kk++)
        qf[kk] = *reinterpret_cast<const bf16x8*>(&qbuf[base + (size_t)q*DK_ + kk*32 + l4*8]);

    const uint2* mb32 = reinterpret_cast<const uint2*>(mbits + ((size_t)b*L_ + q) * (L_/64));

    f32x4 oacc[4];
    #pragma unroll
    for (int nt = 0; nt < 4; nt++) oacc[nt] = (f32x4){0.f, 0.f, 0.f, 0.f};
    f32x4 lacc = (f32x4){0.f, 0.f, 0.f, 0.f};     // row-sum accumulator (MFMA pipe)

    uint4v onesu = {0x3F803F80u, 0x3F803F80u, 0x3F803F80u, 0x3F803F80u};
    const bf16x8 onesv = *reinterpret_cast<const bf16x8*>(&onesu);

    #define STAGE(kd, vd, gk, gv) do {                                               \
        __builtin_amdgcn_global_load_lds(                                            \
            (const __attribute__((address_space(1))) void*)(gk),                     \
            (__attribute__((address_space(3))) void*)(kd), 16, 0, 0);                \
        __builtin_amdgcn_global_load_lds(                                            \
            (const __attribute__((address_space(1))) void*)(gv),                     \
            (__attribute__((address_space(3))) void*)(vd), 16, 0, 0);                \
    } while (0)

    #define BODY(BOFF, mlo, mhi) do {                                               \
        f32x4 sfr[4];                                                                \
        __builtin_amdgcn_s_setprio(1);                                               \
        _Pragma("unroll")                                                            \
        for (int ct = 0; ct < 4; ct++) {                                             \
            bf16x8 kf0 = *reinterpret_cast<const bf16x8*>(pa + (BOFF) + ct*2048);    \
            bf16x8 kf1 = *reinterpret_cast<const bf16x8*>(pb + (BOFF) + ct*2048);    \
            f32x4 a = (f32x4){0.f, 0.f, 0.f, 0.f};                                   \
            a = __builtin_amdgcn_mfma_f32_16x16x32_bf16(kf0, qf[0], a, 0, 0, 0);     \
            a = __builtin_amdgcn_mfma_f32_16x16x32_bf16(kf1, qf[1], a, 0, 0, 0);     \
            sfr[ct] = a;                                                             \
        }                                                                            \
        __builtin_amdgcn_s_setprio(0);                                               \
        unsigned pu[8];                                                              \
        _Pragma("unroll")                                                            \
        for (int ct = 0; ct < 4; ct++) {                                             \
            const unsigned nib = ((((ct) < 2) ? (mlo) : (mhi))                       \
                                  >> ((ct & 1)*16 + l4*4)) & 0xFu;                   \
            float p0 = exp2_raw((nib & 1u) ? sfr[ct][0] : MASK_VALF);                \
            float p1 = exp2_raw((nib & 2u) ? sfr[ct][1] : MASK_VALF);                \
            float p2 = exp2_raw((nib & 4u) ? sfr[ct][2] : MASK_VALF);                \
            float p3 = exp2_raw((nib & 8u) ? sfr[ct][3] : MASK_VALF);                \
            pu[ct*2]     = cvt_pk_bf16(p0, p1);                                      \
            pu[ct*2 + 1] = cvt_pk_bf16(p2, p3);                                      \
        }                                                                            \
        uint4v a0v = {pu[0], pu[1], pu[2], pu[3]};                                   \
        uint4v a1v = {pu[4], pu[5], pu[6], pu[7]};                                   \
        const bf16x8 af0 = *reinterpret_cast<const bf16x8*>(&a0v);                   \
        const bf16x8 af1 = *reinterpret_cast<const bf16x8*>(&a1v);                   \
        __builtin_amdgcn_s_setprio(1);                                               \
        lacc = __builtin_amdgcn_mfma_f32_16x16x32_bf16(af0, onesv, lacc, 0, 0, 0);   \
        lacc = __builtin_amdgcn_mfma_f32_16x16x32_bf16(af1, onesv, lacc, 0, 0, 0);   \
        _Pragma("unroll")                                                            \
        for (int nt = 0; nt < 4; nt++) {                                             \
            bf16x8 vf0 = *reinterpret_cast<const bf16x8*>(pa + (BOFF) + 8192 + nt*2048); \
            bf16x8 vf1 = *reinterpret_cast<const bf16x8*>(pb + (BOFF) + 8192 + nt*2048); \
            oacc[nt] = __builtin_amdgcn_mfma_f32_16x16x32_bf16(af0, vf0, oacc[nt], 0, 0, 0); \
            oacc[nt] = __builtin_amdgcn_mfma_f32_16x16x32_bf16(af1, vf1, oacc[nt], 0, 0, 0); \
        }                                                                            \
        __builtin_amdgcn_s_setprio(0);                                               \
    } while (0)

    STAGE(kd0, vd0, gkA, gvA);
    uint2 mwv = mb32[0], mwn;

    for (int kt = 0; kt < L_/64; kt += 2) {
        // even tile (buf 0 at offset 0)
        __syncthreads();
        STAGE(kd1, vd1, gkB, gvB);
        mwn = mb32[kt + 1];
        BODY(0, mwv.x, mwv.y);
        mwv = mwn;
        gkA += 16384; gvA += 256;
        // odd tile (buf 1 at offset 16384)
        __syncthreads();
        if (kt + 2 < L_/64) { STAGE(kd0, vd0, gkA, gvA); mwn = mb32[kt + 2]; }
        BODY(16384, mwv.x, mwv.y);
        mwv = mwn;
        gkB += 16384; gvB += 256;
    }
    #undef STAGE
    #undef BODY

    // epilogue: lane's O-rows are q = qt0 + w*16 + l4*4 + r, col d = nt*16 + l15;
    // lacc[r] already holds that row's l — no cross-lane reduction needed.
    #pragma unroll
    for (int nt = 0; nt < 4; nt++) {
        #pragma unroll
        for (int r = 0; r < 4; r++) {
            const int qg = qt0 + w*16 + l4*4 + r;
            const float ov = oacc[nt][r] / lacc[r];
            zb[((size_t)b*L_ + qg)*C_ + h*DK_ + nt*16 + l15] = f2bf(ov);
        }
    }
}

extern "C" void kernel_launch(void* const* d_in, const int* in_sizes, int n_in,
                              void* d_out, int out_size, void* d_ws, size_t ws_size,
                              hipStream_t stream)
{
    (void)in_sizes; (void)n_in; (void)out_size; (void)ws_size;
    const float* qx = (const float*)d_in[0];
    const float* kx = (const float*)d_in[1];
    const float* vx = (const float*)d_in[2];
    const int*   mp = (const int*)d_in[3];
    const float* lg = (const float*)d_in[4];
    const float* lbt= (const float*)d_in[5];
    const float* wq = (const float*)d_in[6];
    const float* bq = (const float*)d_in[7];
    const float* wk = (const float*)d_in[8];
    const float* bk = (const float*)d_in[9];
    const float* wv = (const float*)d_in[10];
    const float* bv = (const float*)d_in[11];
    const float* wo = (const float*)d_in[12];
    const float* bo = (const float*)d_in[13];
    float* out = (float*)d_out;

    short* ws0 = (short*)d_ws;
    short* qn  = ws0;
    short* kn  = qn + (size_t)M_*C_;
    short* vn  = kn + (size_t)M_*C_;
    short* wqt = vn + (size_t)M_*C_;
    short* wkt = wqt + 1024*1024;
    short* wvt = wkt + 1024*1024;
    short* wot = wvt + 1024*1024;
    short* qbuf = wot + 1024*1024;
    short* kbuf = qbuf + (size_t)M_*C_;
    short* vtb  = kbuf + (size_t)M_*C_;
    short* zbuf = vtb + (size_t)M_*C_;
    unsigned long long* mbits = (unsigned long long*)(zbuf + (size_t)M_*C_);

    hipLaunchKernelGGL(prep_kernel, dim3(3*M_ + 4096 + (B_*L_*L_/64)/4), dim3(256), 0, stream,
                       qx, kx, vx, lg, lbt, qn, kn, vn,
                       wq, wk, wv, wo, wqt, wkt, wvt, wot, mp, mbits);
    hipLaunchKernelGGL(gemm_proj, dim3(256, 3), dim3(256), 0, stream,
                       qn, kn, vn, wqt, wkt, wvt, bq, bk, bv, qbuf, kbuf, vtb);
    hipLaunchKernelGGL(attn_kernel, dim3(512), dim3(512), 0, stream,
                       qbuf, kbuf, vtb, mbits, zbuf);
    hipLaunchKernelGGL(gemm_out_k, dim3(512), dim3(256), 0, stream,
                       zbuf, wot, bo, out);
}

// Round 12
// 131.493 us; speedup vs baseline: 1.0100x; 1.0100x over previous
//
#include <hip/hip_runtime.h>
#include <hip/hip_bf16.h>

#define B_ 2
#define L_ 2048
#define C_ 1024
#define H_ 16
#define DK_ 64
#define M_ (B_*L_)            // 4096 rows
#define MASK_VALF (-32767.0f)
#define LOG2E 1.44269504088896f

typedef __attribute__((ext_vector_type(8))) short bf16x8;
typedef __attribute__((ext_vector_type(4))) float f32x4;
typedef __attribute__((ext_vector_type(4))) unsigned uint4v;

static __device__ __forceinline__ short f2bf(float f) {
    __hip_bfloat16 h = __float2bfloat16(f);
    return *reinterpret_cast<short*>(&h);
}

// raw v_exp_f32: 1 TRANS inst, flushes exp2(-32767) -> 0 (no libm range fixup)
static __device__ __forceinline__ float exp2_raw(float x) {
    float r;
    asm("v_exp_f32 %0, %1" : "=v"(r) : "v"(x));
    return r;
}
// pack 2 f32 -> 2 bf16 (RNE) in one inst
static __device__ __forceinline__ unsigned cvt_pk_bf16(float lo, float hi) {
    unsigned r;
    asm("v_cvt_pk_bf16_f32 %0, %1, %2" : "=v"(r) : "v"(lo), "v"(hi));
    return r;
}

// ---------------- Fused prep: LN | wconv | maskpack (grid-partitioned) ----------------
__global__ __launch_bounds__(256) void prep_kernel(
    const float* __restrict__ qx, const float* __restrict__ kx, const float* __restrict__ vx,
    const float* __restrict__ g, const float* __restrict__ bias,
    short* __restrict__ qn, short* __restrict__ kn, short* __restrict__ vn,
    const float* __restrict__ wq, const float* __restrict__ wk,
    const float* __restrict__ wv, const float* __restrict__ wo,
    short* __restrict__ wqt, short* __restrict__ wkt,
    short* __restrict__ wvt, short* __restrict__ wot,
    const int* __restrict__ mask, unsigned long long* __restrict__ bits)
{
    const int bid = blockIdx.x;
    const int t = threadIdx.x;

    if (bid < 3*M_) {                          // ---- LayerNorm ----
        const int row = bid & (M_ - 1);
        const int which = bid >> 12;
        const float* src = (which == 0) ? qx : (which == 1) ? kx : vx;
        short* dst = (which == 0) ? qn : (which == 1) ? kn : vn;
        src += (size_t)row * C_;
        dst += (size_t)row * C_;
        float4 xv = reinterpret_cast<const float4*>(src)[t];
        float s  = xv.x + xv.y + xv.z + xv.w;
        float s2 = xv.x*xv.x + xv.y*xv.y + xv.z*xv.z + xv.w*xv.w;
        #pragma unroll
        for (int off = 32; off > 0; off >>= 1) {
            s  += __shfl_down(s, off);
            s2 += __shfl_down(s2, off);
        }
        __shared__ float red[8];
        const int wid = t >> 6, lane = t & 63;
        if (lane == 0) { red[wid] = s; red[4 + wid] = s2; }
        __syncthreads();
        const float ts  = red[0] + red[1] + red[2] + red[3];
        const float ts2 = red[4] + red[5] + red[6] + red[7];
        const float mu  = ts * (1.0f / C_);
        const float var = ts2 * (1.0f / C_) - mu * mu;
        const float rs  = rsqrtf(var + 1e-5f);
        float4 gv = reinterpret_cast<const float4*>(g)[t];
        float4 bv = reinterpret_cast<const float4*>(bias)[t];
        short4 o;
        o.x = f2bf((xv.x - mu) * rs * gv.x + bv.x);
        o.y = f2bf((xv.y - mu) * rs * gv.y + bv.y);
        o.z = f2bf((xv.z - mu) * rs * gv.z + bv.z);
        o.w = f2bf((xv.w - mu) * rs * gv.w + bv.w);
        reinterpret_cast<short4*>(dst)[t] = o;
    } else if (bid < 3*M_ + 4096) {            // ---- weight transpose+convert ----
        const int b2 = bid - 3*M_;
        const int mz = b2 >> 10;
        const int bx = b2 & 31, by = (b2 >> 5) & 31;
        const float* w = (mz==0)?wq:(mz==1)?wk:(mz==2)?wv:wo;
        short* wt = (mz==0)?wqt:(mz==1)?wkt:(mz==2)?wvt:wot;
        __shared__ float tile[32][33];
        const int tx = t & 31, ty = t >> 5;    // 32 x 8
        const int k0 = bx * 32, n0 = by * 32;
        #pragma unroll
        for (int r = 0; r < 4; r++) {
            const int k = k0 + ty + r*8;
            tile[ty + r*8][tx] = w[(size_t)k * 1024 + n0 + tx];
        }
        __syncthreads();
        #pragma unroll
        for (int r = 0; r < 4; r++) {
            const int n = n0 + ty + r*8;
            wt[(size_t)n * 1024 + k0 + tx] = f2bf(tile[tx][ty + r*8]);
        }
    } else {                                    // ---- mask pack ----
        const int b3 = bid - (3*M_ + 4096);
        const int gw = b3 * 4 + (t >> 6);       // word index 0..131071
        const int lane = t & 63;
        const int k = (gw & 31) * 64 + lane;
        const int rowq = gw >> 5;               // b*L + q
        const int v = mask[(size_t)rowq * L_ + k];
        unsigned long long bal = __ballot(v != 0);
        if (lane == 0) bits[gw] = bal;
    }
}

// ---------------- GEMM core (double-buffered): C128x128 = A * Bt^T, BK=32 ----------------
// lds must be 16384 shorts (32 KB): 2 buffers x (A 128x32 | B 128x32).
__device__ __forceinline__ void gemm_core_128(
    const short* __restrict__ Abf, const short* __restrict__ Bt,
    int m0, int n0, short* lds, f32x4 (&acc)[4][4])
{
    const int t = threadIdx.x, w = t >> 6, l = t & 63;
    const int wm = w >> 1, wn = w & 1;
    const int l15 = l & 15, l4 = l >> 4;
    const int srow = t >> 2, scol = (t & 3) * 8;
    const short* aS = Abf + (size_t)(m0 + srow) * 1024 + scol;
    const short* bS = Bt  + (size_t)(n0 + srow) * 1024 + scol;
    char* lb = (char*)lds;
    const int wb = w * 1024;

    #define GSTAGE(buf, kt) do {                                                   \
        const int ko = (kt) * 32;                                                  \
        char* dst = lb + (buf)*16384;                                              \
        __builtin_amdgcn_global_load_lds(                                          \
            (const __attribute__((address_space(1))) void*)(aS + ko),              \
            (__attribute__((address_space(3))) void*)(dst + wb), 16, 0, 0);        \
        __builtin_amdgcn_global_load_lds(                                          \
            (const __attribute__((address_space(1))) void*)(aS + 64*1024 + ko),    \
            (__attribute__((address_space(3))) void*)(dst + wb + 4096), 16, 0, 0); \
        __builtin_amdgcn_global_load_lds(                                          \
            (const __attribute__((address_space(1))) void*)(bS + ko),              \
            (__attribute__((address_space(3))) void*)(dst + 8192 + wb), 16, 0, 0); \
        __builtin_amdgcn_global_load_lds(                                          \
            (const __attribute__((address_space(1))) void*)(bS + 64*1024 + ko),    \
            (__attribute__((address_space(3))) void*)(dst + 8192 + wb + 4096), 16, 0, 0); \
    } while (0)

    GSTAGE(0, 0);
    for (int kt = 0; kt < 32; ++kt) {
        __syncthreads();                            // drains tile kt's loads
        if (kt + 1 < 32) GSTAGE((kt + 1) & 1, kt + 1);   // prefetch overlaps compute
        const short* Lb = lds + (kt & 1) * 8192;
        bf16x8 af[4], bfr[4];
        #pragma unroll
        for (int fm = 0; fm < 4; fm++)
            af[fm] = *reinterpret_cast<const bf16x8*>(&Lb[(wm*64 + fm*16 + l15)*32 + l4*8]);
        #pragma unroll
        for (int fn = 0; fn < 4; fn++)
            bfr[fn] = *reinterpret_cast<const bf16x8*>(&Lb[4096 + (wn*64 + fn*16 + l15)*32 + l4*8]);
        #pragma unroll
        for (int fm = 0; fm < 4; fm++)
            #pragma unroll
            for (int fn = 0; fn < 4; fn++)
                acc[fm][fn] = __builtin_amdgcn_mfma_f32_16x16x32_bf16(af[fm], bfr[fn], acc[fm][fn], 0, 0, 0);
    }
    #undef GSTAGE
}

// ---------------- Projections: q/k/v = LN(x) @ W + b, split heads ----------------
// q pre-scaled by (1/8)*log2e (exp2-domain softmax).
// V written TRANSPOSED per head with k-slot permutation within each 64-block:
// slot(k) = (k&~63) | (qd*32 + g*8 + h*4 + r) for k%64 = qd*32 + h*16 + g*4 + r.
// XCD-aware block swizzle: 256 blocks/slice, 256%8==0 -> bijective.
__global__ __launch_bounds__(256) void gemm_proj(
    const short* __restrict__ qn, const short* __restrict__ kn, const short* __restrict__ vn,
    const short* __restrict__ wqt, const short* __restrict__ wkt, const short* __restrict__ wvt,
    const float* __restrict__ bq, const float* __restrict__ bk, const float* __restrict__ bv,
    short* __restrict__ qb, short* __restrict__ kb, short* __restrict__ vtb)
{
    const int pi = blockIdx.y;
    const short* Abf = (pi==0)?qn:(pi==1)?kn:vn;
    const short* Bt  = (pi==0)?wqt:(pi==1)?wkt:wvt;
    const float* bias= (pi==0)?bq:(pi==1)?bk:bv;
    short* outp      = (pi==0)?qb:(pi==1)?kb:vtb;
    const float scale = (pi==0)?(0.125f*LOG2E):1.0f;

    __shared__ short lds[16384];
    const int bx0 = blockIdx.x;
    const int bx = (bx0 & 7) * 32 + (bx0 >> 3);     // XCD swizzle (bijective, 256%8==0)
    const int m0 = (bx >> 3) * 128, n0 = (bx & 7) * 128;
    f32x4 acc[4][4] = {};
    gemm_core_128(Abf, Bt, m0, n0, lds, acc);

    const int t = threadIdx.x, w = t >> 6, l = t & 63;
    const int wm = w >> 1, wn = w & 1, l15 = l & 15, l4 = l >> 4;
    #pragma unroll
    for (int fn = 0; fn < 4; fn++) {
        const int col = n0 + wn*64 + fn*16 + l15;
        const float bsv = bias[col];
        const int h = col >> 6, dk = col & 63;
        #pragma unroll
        for (int fm = 0; fm < 4; fm++) {
            const int row0 = m0 + wm*64 + fm*16 + l4*4;
            const int bb = row0 >> 11, lr0 = row0 & (L_ - 1);
            if (pi == 2) {
                // x = lr0 & 63 = fm*16 + l4*4; perm: qd=fm>>1, h=fm&1, g=l4
                const int lrp = (lr0 & ~63) | ((fm >> 1)*32 + l4*8 + (fm & 1)*4);
                short4 s4;
                #pragma unroll
                for (int r = 0; r < 4; r++)
                    ((short*)&s4)[r] = f2bf(acc[fm][fn][r] + bsv);
                *reinterpret_cast<short4*>(
                    &outp[(((size_t)bb*H_ + h)*DK_ + dk)*L_ + lrp]) = s4;
            } else {
                #pragma unroll
                for (int r = 0; r < 4; r++) {
                    const float vvf = (acc[fm][fn][r] + bsv) * scale;
                    outp[(((size_t)bb*H_ + h)*L_ + lr0 + r)*DK_ + dk] = f2bf(vvf);
                }
            }
        }
    }
}

// ---------------- Output projection: out = z @ wo + bo (fp32 out), 64x128 tiles ----------
// 512 blocks (2/CU), 4 waves. Wave (wm,wn) owns 32x64; acc[2][4]. XCD swizzle.
__global__ __launch_bounds__(256) void gemm_out_k(
    const short* __restrict__ zb, const short* __restrict__ wot,
    const float* __restrict__ bo, float* __restrict__ out)
{
    __shared__ short lds[12288];   // 2 x (A 64x32 = 2048 sh | B 128x32 = 4096 sh)
    const int t = threadIdx.x, w = t >> 6, l = t & 63;
    const int wm = w >> 1, wn = w & 1;
    const int l15 = l & 15, l4 = l >> 4;
    const int bx0 = blockIdx.x;
    const int bx = (bx0 & 7) * 64 + (bx0 >> 3);     // XCD swizzle (512%8==0)
    const int m0 = (bx >> 3) * 64, n0 = (bx & 7) * 128;

    const int srow = l >> 2, scol = (l & 3) * 8;     // 16 rows x 64B per 1KB chunk
    const short* aS = zb  + (size_t)(m0 + w*16 + srow) * 1024 + scol;
    const short* bS = wot + (size_t)(n0 + w*32 + srow) * 1024 + scol;
    char* lb = (char*)lds;

    f32x4 acc[2][4] = {};

    #define OSTAGE(buf, kt) do {                                                    \
        const int ko = (kt) * 32;                                                   \
        char* dst = lb + (buf)*12288;                                               \
        __builtin_amdgcn_global_load_lds(                                           \
            (const __attribute__((address_space(1))) void*)(aS + ko),               \
            (__attribute__((address_space(3))) void*)(dst + w*1024), 16, 0, 0);     \
        __builtin_amdgcn_global_load_lds(                                           \
            (const __attribute__((address_space(1))) void*)(bS + ko),               \
            (__attribute__((address_space(3))) void*)(dst + 4096 + w*2048), 16, 0, 0); \
        __builtin_amdgcn_global_load_lds(                                           \
            (const __attribute__((address_space(1))) void*)(bS + 16*1024 + ko),     \
            (__attribute__((address_space(3))) void*)(dst + 4096 + w*2048 + 1024), 16, 0, 0); \
    } while (0)

    OSTAGE(0, 0);
    for (int kt = 0; kt < 32; ++kt) {
        __syncthreads();
        if (kt + 1 < 32) OSTAGE((kt + 1) & 1, kt + 1);
        const short* Lb = lds + (kt & 1) * 6144;
        bf16x8 af[2], bfr[4];
        #pragma unroll
        for (int fm = 0; fm < 2; fm++)
            af[fm] = *reinterpret_cast<const bf16x8*>(&Lb[(wm*32 + fm*16 + l15)*32 + l4*8]);
        #pragma unroll
        for (int fn = 0; fn < 4; fn++)
            bfr[fn] = *reinterpret_cast<const bf16x8*>(&Lb[2048 + (wn*64 + fn*16 + l15)*32 + l4*8]);
        #pragma unroll
        for (int fm = 0; fm < 2; fm++)
            #pragma unroll
            for (int fn = 0; fn < 4; fn++)
                acc[fm][fn] = __builtin_amdgcn_mfma_f32_16x16x32_bf16(af[fm], bfr[fn], acc[fm][fn], 0, 0, 0);
    }
    #undef OSTAGE

    #pragma unroll
    for (int fn = 0; fn < 4; fn++) {
        const int col = n0 + wn*64 + fn*16 + l15;
        const float bsv = bo[col];
        #pragma unroll
        for (int fm = 0; fm < 2; fm++) {
            #pragma unroll
            for (int r = 0; r < 4; r++) {
                const int row = m0 + wm*32 + fm*16 + l4*4 + r;
                out[(size_t)row * C_ + col] = acc[fm][fn][r] + bsv;
            }
        }
    }
}

// ---------------- Flash attention v12: 2 KV-tiles per barrier (64KB LDS) ----------------
// Grid caps occupancy at 2 blocks/CU, so 64KB LDS is free (v10/v11 A/B). Buffers hold
// 2 tiles each; barrier count 32 -> 16. Mask words pre-shifted by l4*4 so bit tests use
// compile-time positions; per-phase mask load is one aligned uint4 (2 tiles).
__global__ __launch_bounds__(512) void attn_kernel(
    const short* __restrict__ qbuf, const short* __restrict__ kbuf, const short* __restrict__ vt,
    const unsigned long long* __restrict__ mbits, short* __restrict__ zb)
{
    __shared__ char SM[65536];    // [buf:2][tile:2][K 8KB | V 8KB]
    const int t = threadIdx.x, w = t >> 6, l = t & 63;
    const int l15 = l & 15, l4 = l >> 4;
    const int bid = blockIdx.x;
    const int bh = bid & 31, qb = bid >> 5;
    const int qt0 = qb * 128;
    const int b = bh >> 4, h = bh & 15;
    const size_t base  = (size_t)bh * L_ * DK_;   // q,k: [l][d]
    const size_t vbase = (size_t)bh * DK_ * L_;   // vt:  [d][k-permuted]

    const int q = qt0 + w*16 + l15;               // this lane's softmax row

    // staging geometry (wave w stages LDS rows w*8..w*8+7; swizzled source)
    const int srow = w*8 + (l >> 3);
    const int scolb = ((l & 7) * 16) ^ ((srow & 7) << 4);

    // persistent global staging pointers; advance 2 tiles per STAGE2 call
    const char* gk = (const char*)(kbuf + base + (size_t)srow*DK_) + scolb;
    const char* gv = (const char*)(vt + vbase + (size_t)srow*L_) + scolb;

    // per-lane LDS read bases; all reads = base + compile-time immediate
    const int sw = (l15 & 7) << 4;
    const char* pa = SM + l15*128 + ((l4*16) ^ sw);
    const char* pb = SM + l15*128 + ((64 + l4*16) ^ sw);
    const int l4s = l4 * 4;                       // mask pre-shift amount

    bf16x8 qf[2];
    #pragma unroll
    for (int kk = 0; kk < 2; kk++)
        qf[kk] = *reinterpret_cast<const bf16x8*>(&qbuf[base + (size_t)q*DK_ + kk*32 + l4*8]);

    const uint4* mq4 = reinterpret_cast<const uint4*>(mbits + ((size_t)b*L_ + q) * (L_/64));

    f32x4 oacc[4];
    #pragma unroll
    for (int nt = 0; nt < 4; nt++) oacc[nt] = (f32x4){0.f, 0.f, 0.f, 0.f};
    f32x4 lacc = (f32x4){0.f, 0.f, 0.f, 0.f};     // row-sum accumulator (MFMA pipe)

    uint4v onesu = {0x3F803F80u, 0x3F803F80u, 0x3F803F80u, 0x3F803F80u};
    const bf16x8 onesv = *reinterpret_cast<const bf16x8*>(&onesu);

    // stage 2 consecutive KV tiles into buffer at byte offset DB; advance pointers
    #define STAGE2(DB) do {                                                          \
        __builtin_amdgcn_global_load_lds(                                            \
            (const __attribute__((address_space(1))) void*)(gk),                     \
            (__attribute__((address_space(3))) void*)(SM + (DB) + w*1024), 16, 0, 0); \
        __builtin_amdgcn_global_load_lds(                                            \
            (const __attribute__((address_space(1))) void*)(gv),                     \
            (__attribute__((address_space(3))) void*)(SM + (DB) + 8192 + w*1024), 16, 0, 0); \
        __builtin_amdgcn_global_load_lds(                                            \
            (const __attribute__((address_space(1))) void*)(gk + 8192),              \
            (__attribute__((address_space(3))) void*)(SM + (DB) + 16384 + w*1024), 16, 0, 0); \
        __builtin_amdgcn_global_load_lds(                                            \
            (const __attribute__((address_space(1))) void*)(gv + 128),               \
            (__attribute__((address_space(3))) void*)(SM + (DB) + 24576 + w*1024), 16, 0, 0); \
        gk += 16384; gv += 256;                                                      \
    } while (0)

    #define BODY(BOFF, mlo, mhi) do {                                               \
        f32x4 sfr[4];                                                                \
        __builtin_amdgcn_s_setprio(1);                                               \
        _Pragma("unroll")                                                            \
        for (int ct = 0; ct < 4; ct++) {                                             \
            bf16x8 kf0 = *reinterpret_cast<const bf16x8*>(pa + (BOFF) + ct*2048);    \
            bf16x8 kf1 = *reinterpret_cast<const bf16x8*>(pb + (BOFF) + ct*2048);    \
            f32x4 a = (f32x4){0.f, 0.f, 0.f, 0.f};                                   \
            a = __builtin_amdgcn_mfma_f32_16x16x32_bf16(kf0, qf[0], a, 0, 0, 0);     \
            a = __builtin_amdgcn_mfma_f32_16x16x32_bf16(kf1, qf[1], a, 0, 0, 0);     \
            sfr[ct] = a;                                                             \
        }                                                                            \
        __builtin_amdgcn_s_setprio(0);                                               \
        const unsigned msl = (mlo) >> l4s;                                           \
        const unsigned msh = (mhi) >> l4s;                                           \
        unsigned pu[8];                                                              \
        _Pragma("unroll")                                                            \
        for (int ct = 0; ct < 4; ct++) {                                             \
            const unsigned ms = (ct < 2) ? msl : msh;                                \
            const unsigned bp = (ct & 1) * 16;                                       \
            float p0 = exp2_raw((ms & (1u << (bp + 0))) ? sfr[ct][0] : MASK_VALF);   \
            float p1 = exp2_raw((ms & (1u << (bp + 1))) ? sfr[ct][1] : MASK_VALF);   \
            float p2 = exp2_raw((ms & (1u << (bp + 2))) ? sfr[ct][2] : MASK_VALF);   \
            float p3 = exp2_raw((ms & (1u << (bp + 3))) ? sfr[ct][3] : MASK_VALF);   \
            pu[ct*2]     = cvt_pk_bf16(p0, p1);                                      \
            pu[ct*2 + 1] = cvt_pk_bf16(p2, p3);                                      \
        }                                                                            \
        uint4v a0v = {pu[0], pu[1], pu[2], pu[3]};                                   \
        uint4v a1v = {pu[4], pu[5], pu[6], pu[7]};                                   \
        const bf16x8 af0 = *reinterpret_cast<const bf16x8*>(&a0v);                   \
        const bf16x8 af1 = *reinterpret_cast<const bf16x8*>(&a1v);                   \
        __builtin_amdgcn_s_setprio(1);                                               \
        lacc = __builtin_amdgcn_mfma_f32_16x16x32_bf16(af0, onesv, lacc, 0, 0, 0);   \
        lacc = __builtin_amdgcn_mfma_f32_16x16x32_bf16(af1, onesv, lacc, 0, 0, 0);   \
        _Pragma("unroll")                                                            \
        for (int nt = 0; nt < 4; nt++) {                                             \
            bf16x8 vf0 = *reinterpret_cast<const bf16x8*>(pa + (BOFF) + 8192 + nt*2048); \
            bf16x8 vf1 = *reinterpret_cast<const bf16x8*>(pb + (BOFF) + 8192 + nt*2048); \
            oacc[nt] = __builtin_amdgcn_mfma_f32_16x16x32_bf16(af0, vf0, oacc[nt], 0, 0, 0); \
            oacc[nt] = __builtin_amdgcn_mfma_f32_16x16x32_bf16(af1, vf1, oacc[nt], 0, 0, 0); \
        }                                                                            \
        __builtin_amdgcn_s_setprio(0);                                               \
    } while (0)

    STAGE2(0);                                    // tiles 0,1 -> buffer 0
    uint4 mq = mq4[0], mqn;

    for (int it = 0; it < 16; ++it) {
        const int DB  = (it & 1) * 32768;
        const int DBn = ((it + 1) & 1) * 32768;
        __syncthreads();                          // buffer DB staged
        if (it + 1 < 16) { STAGE2(DBn); mqn = mq4[it + 1]; }
        BODY(DB,         mq.x, mq.y);             // tile 2*it
        BODY(DB + 16384, mq.z, mq.w);             // tile 2*it+1
        mq = mqn;
    }
    #undef STAGE2
    #undef BODY

    // epilogue: lane's O-rows are q = qt0 + w*16 + l4*4 + r, col d = nt*16 + l15;
    // lacc[r] already holds that row's l — no cross-lane reduction needed.
    #pragma unroll
    for (int nt = 0; nt < 4; nt++) {
        #pragma unroll
        for (int r = 0; r < 4; r++) {
            const int qg = qt0 + w*16 + l4*4 + r;
            const float ov = oacc[nt][r] / lacc[r];
            zb[((size_t)b*L_ + qg)*C_ + h*DK_ + nt*16 + l15] = f2bf(ov);
        }
    }
}

extern "C" void kernel_launch(void* const* d_in, const int* in_sizes, int n_in,
                              void* d_out, int out_size, void* d_ws, size_t ws_size,
                              hipStream_t stream)
{
    (void)in_sizes; (void)n_in; (void)out_size; (void)ws_size;
    const float* qx = (const float*)d_in[0];
    const float* kx = (const float*)d_in[1];
    const float* vx = (const float*)d_in[2];
    const int*   mp = (const int*)d_in[3];
    const float* lg = (const float*)d_in[4];
    const float* lbt= (const float*)d_in[5];
    const float* wq = (const float*)d_in[6];
    const float* bq = (const float*)d_in[7];
    const float* wk = (const float*)d_in[8];
    const float* bk = (const float*)d_in[9];
    const float* wv = (const float*)d_in[10];
    const float* bv = (const float*)d_in[11];
    const float* wo = (const float*)d_in[12];
    const float* bo = (const float*)d_in[13];
    float* out = (float*)d_out;

    short* ws0 = (short*)d_ws;
    short* qn  = ws0;
    short* kn  = qn + (size_t)M_*C_;
    short* vn  = kn + (size_t)M_*C_;
    short* wqt = vn + (size_t)M_*C_;
    short* wkt = wqt + 1024*1024;
    short* wvt = wkt + 1024*1024;
    short* wot = wvt + 1024*1024;
    short* qbuf = wot + 1024*1024;
    short* kbuf = qbuf + (size_t)M_*C_;
    short* vtb  = kbuf + (size_t)M_*C_;
    short* zbuf = vtb + (size_t)M_*C_;
    unsigned long long* mbits = (unsigned long long*)(zbuf + (size_t)M_*C_);

    hipLaunchKernelGGL(prep_kernel, dim3(3*M_ + 4096 + (B_*L_*L_/64)/4), dim3(256), 0, stream,
                       qx, kx, vx, lg, lbt, qn, kn, vn,
                       wq, wk, wv, wo, wqt, wkt, wvt, wot, mp, mbits);
    hipLaunchKernelGGL(gemm_proj, dim3(256, 3), dim3(256), 0, stream,
                       qn, kn, vn, wqt, wkt, wvt, bq, bk, bv, qbuf, kbuf, vtb);
    hipLaunchKernelGGL(attn_kernel, dim3(512), dim3(512), 0, stream,
                       qbuf, kbuf, vtb, mbits, zbuf);
    hipLaunchKernelGGL(gemm_out_k, dim3(512), dim3(256), 0, stream,
                       zbuf, wot, bo, out);
}